// Round 1
// 299.313 us; speedup vs baseline: 1.0370x; 1.0370x over previous
//
#include <hip/hip_runtime.h>

typedef __bf16 bf16;
typedef __attribute__((ext_vector_type(8))) __bf16 bf16x8;
typedef __attribute__((ext_vector_type(4))) __bf16 bf16x4;
typedef __attribute__((ext_vector_type(4))) float f32x4;

static __device__ __forceinline__ f32x4 mfma16(bf16x8 a, bf16x8 b, f32x4 c) {
    return __builtin_amdgcn_mfma_f32_16x16x32_bf16(a, b, c, 0, 0, 0);
}

// async global->LDS, 16B per lane; lds base must be wave-uniform
static __device__ __forceinline__ void gll16(const bf16* g, bf16* l) {
    __builtin_amdgcn_global_load_lds(
        (const __attribute__((address_space(1))) unsigned int*)g,
        (__attribute__((address_space(3))) unsigned int*)l, 16, 0, 0);
}

// =====================================================================
// x fp32 -> bf16 (once; result aliased into the Apre workspace slot)
// =====================================================================
__global__ __launch_bounds__(256) void xcvt_kernel(
    const float* __restrict__ x, bf16* __restrict__ xb)
{
    size_t i = ((size_t)blockIdx.x * 256 + threadIdx.x) * 8;
    float4 a0 = *(const float4*)&x[i];
    float4 a1 = *(const float4*)&x[i + 4];
    bf16x8 v = {(bf16)a0.x, (bf16)a0.y, (bf16)a0.z, (bf16)a0.w,
                (bf16)a1.x, (bf16)a1.y, (bf16)a1.z, (bf16)a1.w};
    *(bf16x8*)&xb[i] = v;
}

// =====================================================================
// Weight transpose + convert: W[k][n] (1024x1024 fp32) -> WT[n][k] (bf16)
// =====================================================================
__global__ __launch_bounds__(256) void wtrans_kernel(
    const float* __restrict__ Wq, const float* __restrict__ Wk,
    const float* __restrict__ Wv, const float* __restrict__ Wo,
    bf16* __restrict__ WTqkv, bf16* __restrict__ WTo)
{
    __shared__ bf16 tile[64][65];
    const int bid = blockIdx.x;
    const int mi = bid >> 8;
    const int t  = bid & 255;
    const int tr = t >> 4;
    const int tc = t & 15;
    const int tid = threadIdx.x;

    const float* src = (mi == 0) ? Wq : (mi == 1) ? Wk : (mi == 2) ? Wv : Wo;
    bf16* dst = (mi < 3) ? (WTqkv + (size_t)mi * 1024 * 1024) : WTo;

    #pragma unroll
    for (int i = 0; i < 16; i++) {
        int idx = i * 256 + tid;
        int rl = idx >> 6, cl = idx & 63;
        tile[rl][cl] = (bf16)src[(size_t)(tr * 64 + rl) * 1024 + tc * 64 + cl];
    }
    __syncthreads();
    #pragma unroll
    for (int i = 0; i < 16; i++) {
        int idx = i * 256 + tid;
        int rl = idx >> 6, cl = idx & 63;
        dst[(size_t)(tc * 64 + rl) * 1024 + tr * 64 + cl] = tile[cl][rl];
    }
}

// bias concat (fp32): [b_q | b_k | b_v] -> 3072 floats
__global__ void biascat_kernel(const float* __restrict__ bq, const float* __restrict__ bk,
                               const float* __restrict__ bv, float* __restrict__ dst)
{
    int i = blockIdx.x * 256 + threadIdx.x;
    if (i < 1024) dst[i] = bq[i];
    else if (i < 2048) dst[i] = bk[i - 1024];
    else dst[i] = bv[i - 2048];
}

// =====================================================================
// m97-style GEMM: A bf16, BT bf16, global_load_lds(16B) staging.
// C = A @ BT^T + bias, bf16 out; cols<1024 scaled by QSCALE if scaleQ
// (folds 1/sqrt(d_k) * log2(e) into Q so softmax is a bare exp2).
// =====================================================================
#define QSCALE 0.18033688011112043f   // 0.125 * log2(e)
__global__ __launch_bounds__(256) void gemm_bf16_kernel(
    const bf16* __restrict__ A, const bf16* __restrict__ BT,
    const float* __restrict__ bias, bf16* __restrict__ C,
    int M, int N, int K, int scaleQ)
{
    __shared__ bf16 sA[128 * 32];
    __shared__ bf16 sB[128 * 32];
    const int tid  = threadIdx.x;
    const int lane = tid & 63;
    const int wave = tid >> 6;
    const int quad = lane >> 4;
    const int l15  = lane & 15;
    const int wm = (wave >> 1) * 64;
    const int wn = (wave & 1) * 64;
    const int m0 = blockIdx.y * 128;
    const int n0 = blockIdx.x * 128;

    const f32x4 fzero = {0.f, 0.f, 0.f, 0.f};
    f32x4 acc[4][4];
    #pragma unroll
    for (int i = 0; i < 4; i++)
        #pragma unroll
        for (int j = 0; j < 4; j++) acc[i][j] = fzero;

    float bv[4];
    #pragma unroll
    for (int nc = 0; nc < 4; nc++) bv[nc] = bias[n0 + wn + nc * 16 + l15];

    const int rA = lane >> 2;
    const int cA = (lane & 3) * 8;

    for (int k0 = 0; k0 < K; k0 += 32) {
        #pragma unroll
        for (int p = 0; p < 2; p++) {
            int r16 = (wave * 2 + p) * 16;
            gll16(&A[(size_t)(m0 + r16 + rA) * K + k0 + cA], &sA[r16 * 32]);
            gll16(&BT[(size_t)(n0 + r16 + rA) * K + k0 + cA], &sB[r16 * 32]);
        }
        __syncthreads();

        bf16x8 aF[4], bF[4];
        #pragma unroll
        for (int mc = 0; mc < 4; mc++)
            aF[mc] = *(const bf16x8*)&sA[(wm + mc * 16 + l15) * 32 + quad * 8];
        #pragma unroll
        for (int nc = 0; nc < 4; nc++)
            bF[nc] = *(const bf16x8*)&sB[(wn + nc * 16 + l15) * 32 + quad * 8];

        #pragma unroll
        for (int mc = 0; mc < 4; mc++)
            #pragma unroll
            for (int nc = 0; nc < 4; nc++)
                acc[mc][nc] = mfma16(aF[mc], bF[nc], acc[mc][nc]);
        __syncthreads();
    }

    const float sc = (scaleQ && n0 < 1024) ? QSCALE : 1.0f;
    #pragma unroll
    for (int mc = 0; mc < 4; mc++) {
        #pragma unroll
        for (int reg = 0; reg < 4; reg++) {
            int row = m0 + wm + mc * 16 + quad * 4 + reg;
            size_t base = (size_t)row * N + n0 + wn;
            #pragma unroll
            for (int nc = 0; nc < 4; nc++)
                C[base + nc * 16 + l15] = (bf16)((acc[mc][nc][reg] + bv[nc]) * sc);
        }
    }
}

// Same structure, fp32 output (final projection -> d_out)
__global__ __launch_bounds__(256) void gemm_bf16_f32out_kernel(
    const bf16* __restrict__ A, const bf16* __restrict__ BT,
    const float* __restrict__ bias, float* __restrict__ C,
    int M, int N, int K)
{
    __shared__ bf16 sA[128 * 32];
    __shared__ bf16 sB[128 * 32];
    const int tid  = threadIdx.x;
    const int lane = tid & 63;
    const int wave = tid >> 6;
    const int quad = lane >> 4;
    const int l15  = lane & 15;
    const int wm = (wave >> 1) * 64;
    const int wn = (wave & 1) * 64;
    const int m0 = blockIdx.y * 128;
    const int n0 = blockIdx.x * 128;

    const f32x4 fzero = {0.f, 0.f, 0.f, 0.f};
    f32x4 acc[4][4];
    #pragma unroll
    for (int i = 0; i < 4; i++)
        #pragma unroll
        for (int j = 0; j < 4; j++) acc[i][j] = fzero;

    float bv[4];
    #pragma unroll
    for (int nc = 0; nc < 4; nc++) bv[nc] = bias[n0 + wn + nc * 16 + l15];

    const int rA = lane >> 2;
    const int cA = (lane & 3) * 8;

    for (int k0 = 0; k0 < K; k0 += 32) {
        #pragma unroll
        for (int p = 0; p < 2; p++) {
            int r16 = (wave * 2 + p) * 16;
            gll16(&A[(size_t)(m0 + r16 + rA) * K + k0 + cA], &sA[r16 * 32]);
            gll16(&BT[(size_t)(n0 + r16 + rA) * K + k0 + cA], &sB[r16 * 32]);
        }
        __syncthreads();

        bf16x8 aF[4], bF[4];
        #pragma unroll
        for (int mc = 0; mc < 4; mc++)
            aF[mc] = *(const bf16x8*)&sA[(wm + mc * 16 + l15) * 32 + quad * 8];
        #pragma unroll
        for (int nc = 0; nc < 4; nc++)
            bF[nc] = *(const bf16x8*)&sB[(wn + nc * 16 + l15) * 32 + quad * 8];

        #pragma unroll
        for (int mc = 0; mc < 4; mc++)
            #pragma unroll
            for (int nc = 0; nc < 4; nc++)
                acc[mc][nc] = mfma16(aF[mc], bF[nc], acc[mc][nc]);
        __syncthreads();
    }

    #pragma unroll
    for (int mc = 0; mc < 4; mc++) {
        #pragma unroll
        for (int reg = 0; reg < 4; reg++) {
            int row = m0 + wm + mc * 16 + quad * 4 + reg;
            size_t base = (size_t)row * N + n0 + wn;
            #pragma unroll
            for (int nc = 0; nc < 4; nc++)
                C[base + nc * 16 + l15] = acc[mc][nc][reg] + bv[nc];
        }
    }
}

// =====================================================================
// V transpose: QKVp[b][n][2048 + h*64 + d] -> Vt[b*16+h][d][n]
// =====================================================================
__global__ __launch_bounds__(256) void vtrans_kernel(
    const bf16* __restrict__ QKVp, bf16* __restrict__ Vt)
{
    __shared__ bf16 tile[64][65];
    const int bid = blockIdx.x;
    const int bh = bid >> 5;
    const int nt = bid & 31;
    const int b = bh >> 4, h = bh & 15;
    const int tid = threadIdx.x;

    #pragma unroll
    for (int i = 0; i < 16; i++) {
        int idx = i * 256 + tid;
        int rl = idx >> 6, cl = idx & 63;
        tile[rl][cl] = QKVp[(size_t)(b * 2048 + nt * 64 + rl) * 3072 + 2048 + h * 64 + cl];
    }
    __syncthreads();
    #pragma unroll
    for (int i = 0; i < 16; i++) {
        int idx = i * 256 + tid;
        int rl = idx >> 6, cl = idx & 63;
        Vt[((size_t)bh * 64 + rl) * 2048 + nt * 64 + cl] = tile[cl][rl];
    }
}

// =====================================================================
// Flash attention, P-in-registers, 32 q-rows per wave (2 Q-groups).
// Round-0 change (T14 + dbuf + T5):
//   - LDS double-buffered (2x16KB): ONE barrier per key-tile (was 2).
//   - async-STAGE split: global loads for tile t+1 issued BEFORE the
//     compute of tile t (HBM latency hides under MFMA+exp2); ds_write
//     commit AFTER compute, before the single barrier.  [T14, m214 +17%]
//   - s_setprio(1) around MFMA clusters.                 [T5, m191 +4-7%]
// Math/layout unchanged:
//   S^T = K*Q^T ; P^T = exp2(S^T) packed in-register as PV B-operand
//   O^T = V^T*P ; key-row permute c: (m>>2)*8+(c&1)*4+(m&3)+32(c>>1)
//   Swizzle: phys_granule = logical ^ sw(row), sw(row)=(row&3)|(((row>>3)&1)<<2)
// =====================================================================
__global__ __launch_bounds__(256) void attn_kernel(
    const bf16* __restrict__ QKV, const bf16* __restrict__ Vt,
    bf16* __restrict__ Opre)
{
    __shared__ bf16 sK[2][64 * 64];      // [key][d], swizzled, double-buffered
    __shared__ bf16 sV[2][64 * 64];      // [d][key], swizzled, double-buffered

    const int tid  = threadIdx.x;
    const int lane = tid & 63;
    const int w    = tid >> 6;
    const int quad = lane >> 4;
    const int l15  = lane & 15;
    const int bid = blockIdx.x;
    const int bh = bid >> 4;        // 0..63
    const int qt = bid & 15;
    const int b = bh >> 4, h = bh & 15;
    const int q0 = qt * 128;

    // Q fragments as B-operand [n=q][k=d], two 16-row groups (Q pre-scaled)
    bf16x8 qF[2][2];
    #pragma unroll
    for (int g = 0; g < 2; g++) {
        size_t qrow = (size_t)(b * 2048 + q0 + w * 32 + g * 16 + l15) * 3072 + h * 64;
        qF[g][0] = *(const bf16x8*)&QKV[qrow + quad * 8];
        qF[g][1] = *(const bf16x8*)&QKV[qrow + 32 + quad * 8];
    }

    const f32x4 fzero = {0.f, 0.f, 0.f, 0.f};
    float psum[2] = {0.f, 0.f};
    f32x4 o[2][4];
    #pragma unroll
    for (int g = 0; g < 2; g++)
        #pragma unroll
        for (int mt = 0; mt < 4; mt++) o[g][mt] = fzero;

    const int srow = tid >> 3, sseg = tid & 7;    // staging: 64 rows x 8 granules
    const size_t kbase = (size_t)(b * 2048) * 3072 + 1024 + h * 64;
    const size_t vbase = (size_t)bh * 64 * 2048;
    // swizzled granule for staging writes (p-independent: +32 rows only flips bit5)
    const int sgsw = sseg ^ ((srow & 3) | (((srow >> 3) & 1) << 2));

    // swizzle factors for compute reads (row-dependent parts are l15-only)
    const int swk = (l15 & 3) | (((l15 >> 2) & 1) << 2);  // for S^T K-rows
    const int swv = (l15 & 3) | (((l15 >> 3) & 1) << 2);  // for V rows mt*16+l15

    bf16x8 stK[2], stV[2];    // in-flight staging regs (tile t+1)

    // ---- prologue: stage tile 0 into buffer 0 ----
    #pragma unroll
    for (int p = 0; p < 2; p++) {
        int row = srow + p * 32;
        stK[p] = *(const bf16x8*)&QKV[kbase + (size_t)row * 3072 + sseg * 8];
        stV[p] = *(const bf16x8*)&Vt[vbase + (size_t)row * 2048 + sseg * 8];
    }
    #pragma unroll
    for (int p = 0; p < 2; p++) {
        int row = srow + p * 32;
        *(bf16x8*)&sK[0][row * 64 + sgsw * 8] = stK[p];
        *(bf16x8*)&sV[0][row * 64 + sgsw * 8] = stV[p];
    }
    __syncthreads();

    auto compute_tile = [&](const bf16* sKc, const bf16* sVc) {
        // S^T tiles c=0..3, keys permuted; K frags shared across both q-groups.
        bf16x8 pB[2][2];
        #pragma unroll
        for (int c = 0; c < 4; c++) {
            int kr = ((l15 >> 2) << 3) + ((c & 1) << 2) + (l15 & 3) + ((c >> 1) << 5);
            bf16x8 kA0 = *(const bf16x8*)&sKc[kr * 64 + ((quad ^ swk) * 8)];
            bf16x8 kA1 = *(const bf16x8*)&sKc[kr * 64 + (((4 + quad) ^ swk) * 8)];
            #pragma unroll
            for (int g = 0; g < 2; g++) {
                __builtin_amdgcn_s_setprio(1);
                f32x4 st = mfma16(kA0, qF[g][0], fzero);
                st = mfma16(kA1, qF[g][1], st);
                __builtin_amdgcn_s_setprio(0);
                #pragma unroll
                for (int r = 0; r < 4; r++) {
                    float p = __builtin_amdgcn_exp2f(st[r]);
                    psum[g] += p;
                    pB[g][c >> 1][(c & 1) * 4 + r] = (bf16)p;
                }
            }
        }
        // O^T += V^T . P : V frags shared across both q-groups
        #pragma unroll
        for (int mt = 0; mt < 4; mt++) {
            int vr = mt * 16 + l15;
            bf16x8 vA0 = *(const bf16x8*)&sVc[vr * 64 + ((quad ^ swv) * 8)];
            bf16x8 vA1 = *(const bf16x8*)&sVc[vr * 64 + (((4 + quad) ^ swv) * 8)];
            __builtin_amdgcn_s_setprio(1);
            #pragma unroll
            for (int g = 0; g < 2; g++) {
                o[g][mt] = mfma16(vA0, pB[g][0], o[g][mt]);
                o[g][mt] = mfma16(vA1, pB[g][1], o[g][mt]);
            }
            __builtin_amdgcn_s_setprio(0);
        }
    };

    // ---- main loop: 31 pipelined tiles + 1 epilogue tile ----
    int cur = 0;
    for (int t = 0; t < 31; t++) {
        // (1) issue tile t+1 global loads early -> latency hides under compute
        const int key0 = (t + 1) * 64;
        #pragma unroll
        for (int p = 0; p < 2; p++) {
            int row = srow + p * 32;
            stK[p] = *(const bf16x8*)&QKV[kbase + (size_t)(key0 + row) * 3072 + sseg * 8];
            stV[p] = *(const bf16x8*)&Vt[vbase + (size_t)row * 2048 + key0 + sseg * 8];
        }
        __builtin_amdgcn_sched_barrier(0);   // pin loads above compute

        // (2) compute tile t from buf[cur]
        compute_tile(sK[cur], sV[cur]);

        // (3) commit tile t+1 into buf[cur^1] (waits vmcnt here, post-compute)
        #pragma unroll
        for (int p = 0; p < 2; p++) {
            int row = srow + p * 32;
            *(bf16x8*)&sK[cur ^ 1][row * 64 + sgsw * 8] = stK[p];
            *(bf16x8*)&sV[cur ^ 1][row * 64 + sgsw * 8] = stV[p];
        }
        __syncthreads();
        cur ^= 1;
    }
    compute_tile(sK[cur], sV[cur]);

    // row-sum: lane holds 16-key partials for q=l15 (per group); reduce quads
    #pragma unroll
    for (int g = 0; g < 2; g++) {
        float t = psum[g];
        t += __shfl_xor(t, 16);
        t += __shfl_xor(t, 32);
        float inv = 1.0f / t;
        size_t obase = (size_t)(b * 2048 + q0 + w * 32 + g * 16 + l15) * 1024 + h * 64;
        #pragma unroll
        for (int mt = 0; mt < 4; mt++) {
            bf16x4 ov = {(bf16)(o[g][mt][0] * inv), (bf16)(o[g][mt][1] * inv),
                         (bf16)(o[g][mt][2] * inv), (bf16)(o[g][mt][3] * inv)};
            *(bf16x4*)&Opre[obase + mt * 16 + quad * 4] = ov;
        }
    }
}

// =====================================================================
extern "C" void kernel_launch(void* const* d_in, const int* in_sizes, int n_in,
                              void* d_out, int out_size, void* d_ws, size_t ws_size,
                              hipStream_t stream)
{
    const float* x  = (const float*)d_in[0];
    const float* Wq = (const float*)d_in[1];
    const float* bq = (const float*)d_in[2];
    const float* Wk = (const float*)d_in[3];
    const float* bk = (const float*)d_in[4];
    const float* Wv = (const float*)d_in[5];
    const float* bv = (const float*)d_in[6];
    const float* Wo = (const float*)d_in[7];
    const float* bo = (const float*)d_in[8];
    float* out = (float*)d_out;

    bf16* WTqkv = (bf16*)d_ws;                         // 3072*1024 bf16
    bf16* WTo   = WTqkv + (size_t)3072 * 1024;         // 1024*1024 bf16
    float* bcat = (float*)(WTo + (size_t)1024 * 1024); // 3072 f32 (pad 4096)
    bf16* QKVp  = (bf16*)(bcat + 4096);                // 8192*3072 bf16
    bf16* Vt    = QKVp + (size_t)8192 * 3072;          // 64*64*2048 bf16
    bf16* Apre  = Vt + (size_t)64 * 64 * 2048;         // 8192*1024 bf16
    bf16* xb    = Apre;   // alias: x-as-bf16 lives here until attn overwrites
    (void)ws_size; (void)n_in; (void)in_sizes; (void)out_size;

    xcvt_kernel<<<4096, 256, 0, stream>>>(x, xb);
    wtrans_kernel<<<1024, 256, 0, stream>>>(Wq, Wk, Wv, Wo, WTqkv, WTo);
    biascat_kernel<<<12, 256, 0, stream>>>(bq, bk, bv, bcat);
    gemm_bf16_kernel<<<dim3(24, 64), 256, 0, stream>>>(xb, WTqkv, bcat, QKVp, 8192, 3072, 1024, 1);
    vtrans_kernel<<<2048, 256, 0, stream>>>(QKVp, Vt);
    attn_kernel<<<1024, 256, 0, stream>>>(QKVp, Vt, Apre);
    gemm_bf16_f32out_kernel<<<dim3(8, 64), 256, 0, stream>>>(Apre, WTo, bo, out, 8192, 1024, 1024);
}